// Round 10
// baseline (183.357 us; speedup 1.0000x reference)
//
#include <hip/hip_runtime.h>
#include <math.h>

#define DD 8
#define ZD 16
#define HID 200
#define EPSL 0.1f
#define NKC 7          // K chunks of 32 (200 -> 224)
#define NMT 13         // unit tiles of 16 (200 -> 208)
#define XSTR 200       // halfs per X row (overrun reads spill into next row; A=0 kills them)
#define CSTR 208       // halfs per coeff row
#define WSTR 208       // halfs per staged-weight row
#define NTAN 8
#define NT4 4

#define KSC 1024.0f        // backward-chain scale
#define SSC 64.0f          // tangent-chain scale
#define INV_K (1.0f/1024.0f)
#define INV_KS (1.0f/65536.0f)

typedef _Float16 half8 __attribute__((ext_vector_type(8)));
typedef _Float16 half4v __attribute__((ext_vector_type(4)));
typedef _Float16 half2v __attribute__((ext_vector_type(2)));
typedef float float4v __attribute__((ext_vector_type(4)));

#define S4 (NKC*NMT*64*8)
#define OFF_W1T 0
#define OFF_W2T (S4)
#define OFF_W1  (2*S4)
#define OFF_W2  (3*S4)
#define OFF_W0T (4*S4)
#define OFF_W0  (4*S4 + NMT*64*8)
#define WS_HALFS (4*S4 + NMT*64*8 + NKC*64*8)

// ---------------------------------------------------------------------------
__global__ void prep(const float* __restrict__ W0, const float* __restrict__ W1,
                     const float* __restrict__ W2, _Float16* __restrict__ ws)
{
    int idx = blockIdx.x * 256 + threadIdx.x;
    if (idx >= WS_HALFS) return;
    float v = 0.f;
    if (idx < 4*S4) {
        int arr = idx / S4, e = idx % S4;
        int kc = e / (NMT*64*8); int r = e % (NMT*64*8);
        int mt = r / (64*8); r %= 64*8;
        int lane = r / 8, j = r % 8;
        int m = mt*16 + (lane & 15);
        int k = kc*32 + (lane >> 4)*8 + j;
        if (m < HID && k < HID) {
            if      (arr == 0) v = W1[k*HID + m];
            else if (arr == 1) v = W2[k*HID + m];
            else if (arr == 2) v = W1[m*HID + k];
            else               v = W2[m*HID + k];
        }
    } else if (idx < OFF_W0) {
        int e = idx - OFF_W0T;
        int mt = e / (64*8); int r = e % (64*8);
        int lane = r / 8, j = r % 8;
        int m = mt*16 + (lane & 15);
        int k = (lane >> 4)*8 + j;
        if (m < HID && k < ZD) v = W0[k*HID + m];
    } else {
        int e = idx - OFF_W0;
        int kc = e / (64*8); int r = e % (64*8);
        int lane = r / 8, j = r % 8;
        int m = (lane & 15);
        int k = kc*32 + (lane >> 4)*8 + j;
        if (k < HID) v = W0[m*HID + k];
    }
    ws[idx] = (_Float16)v;
}

// ---------------------------------------------------------------------------
__device__ __forceinline__ half4v pk4(float4v a) {
    half2v lo = __builtin_bit_cast(half2v, __builtin_amdgcn_cvt_pkrtz(a.x, a.y));
    half2v hi = __builtin_bit_cast(half2v, __builtin_amdgcn_cvt_pkrtz(a.z, a.w));
    return __builtin_shufflevector(lo, hi, 0, 1, 2, 3);
}
__device__ __forceinline__ void sig_sp(float x, float& sp, float& sg) {
    float e = __expf(-fabsf(x));
    float r = 1.0f / (1.0f + e);
    sg = (x >= 0.f) ? r : (1.0f - r);
    sp = fmaxf(x, 0.f) + __logf(1.f + e);
}

template<int NTILES, int MTC>
__device__ __forceinline__ void run_mv(const half8* __restrict__ Asw,
                                       const _Float16* __restrict__ Xsrc,
                                       int mt0, int lane,
                                       float4v acc[MTC][NTILES])
{
    const int lm = lane & 15, q = lane >> 4;
    constexpr int PF = (NTILES > 1) ? 2 : NKC;
#pragma unroll
    for (int m = 0; m < MTC; ++m)
#pragma unroll
        for (int n = 0; n < NTILES; ++n)
            acc[m][n] = (float4v){0.f, 0.f, 0.f, 0.f};

    half8 a[MTC][PF];
#pragma unroll
    for (int p = 0; p < PF; ++p)
#pragma unroll
        for (int m = 0; m < MTC; ++m)
            a[m][p] = Asw[(p*NMT + mt0 + m)*64 + lane];

#pragma unroll
    for (int kc = 0; kc < NKC; ++kc) {
        half8 x[NTILES];
#pragma unroll
        for (int n = 0; n < NTILES; ++n)
            x[n] = *(const half8*)(Xsrc + (n*16 + lm)*XSTR + kc*32 + q*8);
        half8 an[MTC];
        if (kc + PF < NKC)
#pragma unroll
            for (int m = 0; m < MTC; ++m)
                an[m] = Asw[((kc+PF)*NMT + mt0 + m)*64 + lane];
#pragma unroll
        for (int m = 0; m < MTC; ++m)
#pragma unroll
            for (int n = 0; n < NTILES; ++n)
                acc[m][n] = __builtin_amdgcn_mfma_f32_16x16x32_f16(a[m][0], x[n], acc[m][n], 0, 0, 0);
#pragma unroll
        for (int m = 0; m < MTC; ++m)
#pragma unroll
            for (int p = 0; p + 1 < PF; ++p) a[m][p] = a[m][p+1];
        if (kc + PF < NKC)
#pragma unroll
            for (int m = 0; m < MTC; ++m) a[m][PF-1] = an[m];
    }
}

// ===========================================================================
// F-kernel: BS=16, forward+backward chain; coeffs -> global cf, g -> global.
// ===========================================================================
__global__ void __launch_bounds__(512, 4)
lnn_fwd(const float* __restrict__ z,
        const float* __restrict__ b0, const float* __restrict__ b1,
        const float* __restrict__ b2, const float* __restrict__ W3,
        const _Float16* __restrict__ ws,
        _Float16* __restrict__ cf, float* __restrict__ g, int N)
{
    __shared__ alignas(16) _Float16 Xa[16*XSTR + 24];
    __shared__ alignas(16) _Float16 Xc[16*XSTR + 24];
    __shared__ alignas(16) _Float16 CfF[2][16*CSTR];  // p0, p1 (for B1/B0)
    __shared__ alignas(16) _Float16 Xz[16*32];
    __shared__ alignas(16) _Float16 bsh[4*WSTR];

    const int tid  = threadIdx.x;
    const int wave = tid >> 6;
    const int lane = tid & 63;
    const int lm   = lane & 15;
    const int q    = lane >> 4;
    const int s0   = blockIdx.x * 16;

    const int mt0 = (wave < 5) ? wave*2 : (10 + (wave - 5));
    const int mtc = (wave < 5) ? 2 : 1;

    const half8* W1Tsw = (const half8*)(ws + OFF_W1T);
    const half8* W2Tsw = (const half8*)(ws + OFF_W2T);
    const half8* W1sw  = (const half8*)(ws + OFF_W1);
    const half8* W2sw  = (const half8*)(ws + OFF_W2);
    const half8* W0Tsw = (const half8*)(ws + OFF_W0T);
    const half8* W0sw  = (const half8*)(ws + OFF_W0);

    {
        int s = tid >> 5, c = tid & 31;
        Xz[tid] = (c < ZD) ? (_Float16)z[(size_t)(s0 + s)*ZD + c] : (_Float16)0.f;
    }
    if (tid < 24) { Xa[16*XSTR + tid] = (_Float16)0.f; Xc[16*XSTR + tid] = (_Float16)0.f; }
    for (int idx = tid; idx < 4*WSTR; idx += 512) {
        int l = idx / WSTR, u = idx % WSTR;
        float v = 0.f;
        if (u < HID) {
            if      (l == 0) v = b0[u];
            else if (l == 1) v = b1[u];
            else if (l == 2) v = b2[u];
            else             v = KSC * W3[u];
        }
        bsh[idx] = (_Float16)v;
    }
    __syncthreads();

    float4v acc1[2][1];

    // F0: a0 = z@W0+b0 ; h0->Xa, p0->CfF0+cf0
    {
        half8 xz = *(const half8*)(Xz + lm*32 + q*8);
#pragma unroll
        for (int m = 0; m < 2; ++m)
            if (m < mtc) {
                acc1[m][0] = (float4v){0.f,0.f,0.f,0.f};
                half8 a = W0Tsw[(mt0 + m)*64 + lane];
                acc1[m][0] = __builtin_amdgcn_mfma_f32_16x16x32_f16(a, xz, acc1[m][0], 0, 0, 0);
                const int ub = (mt0 + m)*16 + q*4;
                const bool padq = (mt0 + m == 12) && (q >= 2);
                half4v bb = *(const half4v*)(&bsh[0*WSTR + ub]);
                float h[4], p[4];
#pragma unroll
                for (int r = 0; r < 4; ++r) {
                    float av = acc1[m][0][r] + (float)bb[r];
                    sig_sp(av, h[r], p[r]);
                }
                half4v pp = pk4((float4v){p[0],p[1],p[2],p[3]});
                if (!padq) *(half4v*)(&Xa[lm*XSTR + ub]) = pk4((float4v){h[0],h[1],h[2],h[3]});
                *(half4v*)(&CfF[0][lm*CSTR + ub]) = pp;
                if (!padq) *(half4v*)(cf + ((size_t)0*N + s0 + lm)*HID + ub) = pp;
            }
    }
    __syncthreads();

    // F1: reads Xa(h0) -> h1->Xc, p1->CfF1+cf1
    {
        if (mtc == 2) run_mv<1,2>(W1Tsw, Xa, mt0, lane, acc1);
        else          run_mv<1,1>(W1Tsw, Xa, mt0, lane, acc1);
#pragma unroll
        for (int m = 0; m < 2; ++m)
            if (m < mtc) {
                const int ub = (mt0 + m)*16 + q*4;
                const bool padq = (mt0 + m == 12) && (q >= 2);
                half4v bb = *(const half4v*)(&bsh[1*WSTR + ub]);
                float h[4], p[4];
#pragma unroll
                for (int r = 0; r < 4; ++r) {
                    float av = acc1[m][0][r] + (float)bb[r];
                    sig_sp(av, h[r], p[r]);
                }
                half4v pp = pk4((float4v){p[0],p[1],p[2],p[3]});
                if (!padq) *(half4v*)(&Xc[lm*XSTR + ub]) = pk4((float4v){h[0],h[1],h[2],h[3]});
                *(half4v*)(&CfF[1][lm*CSTR + ub]) = pp;
                if (!padq) *(half4v*)(cf + ((size_t)1*N + s0 + lm)*HID + ub) = pp;
            }
    }
    __syncthreads();

    // F2: reads Xc(h1) -> d2'->Xa, c2'->cf2
    {
        if (mtc == 2) run_mv<1,2>(W2Tsw, Xc, mt0, lane, acc1);
        else          run_mv<1,1>(W2Tsw, Xc, mt0, lane, acc1);
#pragma unroll
        for (int m = 0; m < 2; ++m)
            if (m < mtc) {
                const int ub = (mt0 + m)*16 + q*4;
                const bool padq = (mt0 + m == 12) && (q >= 2);
                half4v bb = *(const half4v*)(&bsh[2*WSTR + ub]);
                half4v w3 = *(const half4v*)(&bsh[3*WSTR + ub]);
                float d2[4], c2[4];
#pragma unroll
                for (int r = 0; r < 4; ++r) {
                    float av = acc1[m][0][r] + (float)bb[r];
                    float e = __expf(-fabsf(av));
                    float rr = 1.f / (1.f + e);
                    float sg = (av >= 0.f) ? rr : (1.f - rr);
                    float wk = (float)w3[r];
                    d2[r] = wk * sg;
                    c2[r] = wk * sg * (1.f - sg);
                }
                if (!padq) *(half4v*)(&Xa[lm*XSTR + ub]) = pk4((float4v){d2[0],d2[1],d2[2],d2[3]});
                if (!padq) *(half4v*)(cf + ((size_t)2*N + s0 + lm)*HID + ub) = pk4((float4v){c2[0],c2[1],c2[2],c2[3]});
            }
    }
    __syncthreads();

    // B1: reads Xa(d2') -> d1'->Xc, c3->cf3
    {
        if (mtc == 2) run_mv<1,2>(W2sw, Xa, mt0, lane, acc1);
        else          run_mv<1,1>(W2sw, Xa, mt0, lane, acc1);
#pragma unroll
        for (int m = 0; m < 2; ++m)
            if (m < mtc) {
                const int ub = (mt0 + m)*16 + q*4;
                const bool padq = (mt0 + m == 12) && (q >= 2);
                half4v p1 = *(const half4v*)(&CfF[1][lm*CSTR + ub]);
                half4v u1 = pk4(acc1[m][0]);
                half4v one = {(_Float16)1.f,(_Float16)1.f,(_Float16)1.f,(_Float16)1.f};
                if (!padq) *(half4v*)(&Xc[lm*XSTR + ub]) = u1 * p1;
                if (!padq) *(half4v*)(cf + ((size_t)3*N + s0 + lm)*HID + ub) = u1 * (one - p1);
            }
    }
    __syncthreads();

    // B0: reads Xc(d1') -> d0'->Xa, c4->cf4
    {
        if (mtc == 2) run_mv<1,2>(W1sw, Xc, mt0, lane, acc1);
        else          run_mv<1,1>(W1sw, Xc, mt0, lane, acc1);
#pragma unroll
        for (int m = 0; m < 2; ++m)
            if (m < mtc) {
                const int ub = (mt0 + m)*16 + q*4;
                const bool padq = (mt0 + m == 12) && (q >= 2);
                half4v p0 = *(const half4v*)(&CfF[0][lm*CSTR + ub]);
                half4v u0 = pk4(acc1[m][0]);
                half4v one = {(_Float16)1.f,(_Float16)1.f,(_Float16)1.f,(_Float16)1.f};
                half4v d0 = u0 * p0;
                if (!padq) *(half4v*)(&Xa[lm*XSTR + ub]) = d0;
                if (!padq) *(half4v*)(cf + ((size_t)4*N + s0 + lm)*HID + ub) = d0 * (one - p0);
            }
    }
    __syncthreads();

    // g-projection: g[s][z] = (W0 . d0)/K, wave 0
    if (wave == 0) {
        half8 aw[NKC];
#pragma unroll
        for (int kc = 0; kc < NKC; ++kc) aw[kc] = W0sw[kc*64 + lane];
        float4v gv = (float4v){0.f,0.f,0.f,0.f};
#pragma unroll
        for (int kc = 0; kc < NKC; ++kc) {
            half8 x = *(const half8*)(Xa + lm*XSTR + kc*32 + q*8);
            gv = __builtin_amdgcn_mfma_f32_16x16x32_f16(aw[kc], x, gv, 0, 0, 0);
        }
        float4v go; go.x = gv.x*INV_K; go.y = gv.y*INV_K; go.z = gv.z*INV_K; go.w = gv.w*INV_K;
        *(float4v*)(g + (size_t)(s0 + lm)*16 + q*4) = go;
    }
}

// ===========================================================================
// T-kernel: BS=8, tangent chain + Hr + solve; coeffs from global cf.
// ===========================================================================
__global__ void __launch_bounds__(512, 4)
lnn_tan(const float* __restrict__ z, const float* __restrict__ W0,
        const _Float16* __restrict__ ws, const _Float16* __restrict__ cf,
        const float* __restrict__ g, float* __restrict__ out, int N)
{
    __shared__ alignas(16) _Float16 Xt[64*XSTR + 24];
    __shared__ alignas(16) _Float16 Xb[64*XSTR + 24];
    __shared__ alignas(16) _Float16 Cf[5][8*CSTR];
    __shared__ alignas(16) _Float16 w0t[NTAN*WSTR];
    __shared__ alignas(16) float HrS[64*16];

    const int tid  = threadIdx.x;
    const int wave = tid >> 6;
    const int lane = tid & 63;
    const int lm   = lane & 15;
    const int q    = lane >> 4;
    const int s0   = blockIdx.x * 8;

    const int mt0 = (wave < 5) ? wave*2 : (10 + (wave - 5));
    const int mtc = (wave < 5) ? 2 : 1;

    const half8* W1Tsw = (const half8*)(ws + OFF_W1T);
    const half8* W2Tsw = (const half8*)(ws + OFF_W2T);
    const half8* W1sw  = (const half8*)(ws + OFF_W1);
    const half8* W2sw  = (const half8*)(ws + OFF_W2);
    const half8* W0sw  = (const half8*)(ws + OFF_W0);

    // ---- staging ----
    {
        _Float16* cfl = &Cf[0][0];
        for (int idx = tid; idx < 5*8*CSTR; idx += 512) {
            int c = idx / (8*CSTR), r = idx % (8*CSTR);
            int s = r / CSTR, u = r % CSTR;
            cfl[idx] = (u < HID) ? cf[((size_t)c*N + s0 + s)*HID + u] : (_Float16)0.f;
        }
    }
    for (int idx = tid; idx < NTAN*WSTR; idx += 512) {
        int t = idx / WSTR, u = idx % WSTR;
        w0t[idx] = (_Float16)((u < HID) ? SSC * W0[(size_t)(DD + t)*HID + u] : 0.f);
    }
    if (tid < 24) { Xt[64*XSTR + tid] = (_Float16)0.f; Xb[64*XSTR + tid] = (_Float16)0.f; }
    __syncthreads();

    // th0: Xb[row=t*8+s][u] = p0[s][u] * (SSC*W0[8+t][u])
    for (int idx = tid; idx < 64*50; idx += 512) {
        int row = idx / 50, u = (idx % 50)*4;
        int s = row & 7, t = row >> 3;
        half4v p0 = *(const half4v*)(&Cf[0][s*CSTR + u]);
        half4v w0 = *(const half4v*)(&w0t[t*WSTR + u]);
        *(half4v*)(&Xb[row*XSTR + u]) = p0 * w0;
    }
    __syncthreads();

    float4v acc4[2][NT4];
    half4v c3th1[2][NT4];

    // T2: reads Xb(th0) -> th1'->Xt ; carry c3*th1'
    {
        if (mtc == 2) run_mv<NT4,2>(W1Tsw, Xb, mt0, lane, acc4);
        else          run_mv<NT4,1>(W1Tsw, Xb, mt0, lane, acc4);
#pragma unroll
        for (int m = 0; m < 2; ++m)
            if (m < mtc) {
                const int ub = (mt0 + m)*16 + q*4;
                const bool padq = (mt0 + m == 12) && (q >= 2);
                half4v p1 = *(const half4v*)(&Cf[1][(lm & 7)*CSTR + ub]);
                half4v c3 = *(const half4v*)(&Cf[3][(lm & 7)*CSTR + ub]);
#pragma unroll
                for (int n = 0; n < NT4; ++n) {
                    half4v t = pk4(acc4[m][n]) * p1;
                    if (!padq) *(half4v*)(&Xt[(n*16 + lm)*XSTR + ub]) = t;
                    c3th1[m][n] = c3 * t;
                }
            }
    }
    __syncthreads();

    // T3: reads Xt(th1') -> d2dot->Xb
    {
        if (mtc == 2) run_mv<NT4,2>(W2Tsw, Xt, mt0, lane, acc4);
        else          run_mv<NT4,1>(W2Tsw, Xt, mt0, lane, acc4);
#pragma unroll
        for (int m = 0; m < 2; ++m)
            if (m < mtc) {
                const int ub = (mt0 + m)*16 + q*4;
                const bool padq = (mt0 + m == 12) && (q >= 2);
                half4v c2 = *(const half4v*)(&Cf[2][(lm & 7)*CSTR + ub]);
#pragma unroll
                for (int n = 0; n < NT4; ++n)
                    if (!padq) *(half4v*)(&Xb[(n*16 + lm)*XSTR + ub]) = pk4(acc4[m][n]) * c2;
            }
    }
    __syncthreads();

    // T4: reads Xb(d2dot) -> d1dot = v1''*p1 + c3*th1' -> Xt
    {
        if (mtc == 2) run_mv<NT4,2>(W2sw, Xb, mt0, lane, acc4);
        else          run_mv<NT4,1>(W2sw, Xb, mt0, lane, acc4);
#pragma unroll
        for (int m = 0; m < 2; ++m)
            if (m < mtc) {
                const int ub = (mt0 + m)*16 + q*4;
                const bool padq = (mt0 + m == 12) && (q >= 2);
                half4v p1 = *(const half4v*)(&Cf[1][(lm & 7)*CSTR + ub]);
#pragma unroll
                for (int n = 0; n < NT4; ++n)
                    if (!padq) *(half4v*)(&Xt[(n*16 + lm)*XSTR + ub]) = pk4(acc4[m][n]) * p1 + c3th1[m][n];
            }
    }
    __syncthreads();

    // T5: reads Xt(d1dot) -> d0dot = v0''*p0 + c4*(S*t0) -> Xb
    {
        if (mtc == 2) run_mv<NT4,2>(W1sw, Xt, mt0, lane, acc4);
        else          run_mv<NT4,1>(W1sw, Xt, mt0, lane, acc4);
#pragma unroll
        for (int m = 0; m < 2; ++m)
            if (m < mtc) {
                const int ub = (mt0 + m)*16 + q*4;
                const bool padq = (mt0 + m == 12) && (q >= 2);
                half4v p0 = *(const half4v*)(&Cf[0][(lm & 7)*CSTR + ub]);
                half4v c4 = *(const half4v*)(&Cf[4][(lm & 7)*CSTR + ub]);
#pragma unroll
                for (int n = 0; n < NT4; ++n) {
                    int t = n*2 + (lm >> 3);
                    half4v w0 = *(const half4v*)(&w0t[t*WSTR + ub]);
                    if (!padq) *(half4v*)(&Xb[(n*16 + lm)*XSTR + ub]) = pk4(acc4[m][n]) * p0 + c4 * w0;
                }
            }
    }
    __syncthreads();

    // Hr projection: waves 0-3, rows wave*16+lm (reads Xb=d0dot)
    if (wave < 4) {
        half8 aw[NKC];
#pragma unroll
        for (int kc = 0; kc < NKC; ++kc) aw[kc] = W0sw[kc*64 + lane];
        float4v hacc = (float4v){0.f,0.f,0.f,0.f};
#pragma unroll
        for (int kc = 0; kc < NKC; ++kc) {
            half8 x = *(const half8*)(Xb + (wave*16 + lm)*XSTR + kc*32 + q*8);
            hacc = __builtin_amdgcn_mfma_f32_16x16x32_f16(aw[kc], x, hacc, 0, 0, 0);
        }
        int row = wave*16 + lm;   // = t*8 + s
        float4v hv;
        hv.x = hacc.x*INV_KS; hv.y = hacc.y*INV_KS;
        hv.z = hacc.z*INV_KS; hv.w = hacc.w*INV_KS;
        *(float4v*)(&HrS[row*16 + q*4]) = hv;
    }
    __syncthreads();

    // per-sample 8x8 solve
    if (tid < 8) {
        const int s = tid;
        float M[DD][DD], F[DD], v[DD], a[DD];
#pragma unroll
        for (int c = 0; c < DD; ++c) v[c] = z[(size_t)(s0 + s)*ZD + DD + c];
#pragma unroll
        for (int r = 0; r < DD; ++r) {
            float f = g[(size_t)(s0 + s)*16 + r];
#pragma unroll
            for (int c = 0; c < DD; ++c) {
                M[r][c] = HrS[(r*8 + s)*16 + DD + c] + ((r == c) ? 2.f*EPSL : 0.f);
                f -= HrS[(r*8 + s)*16 + c] * v[c];
            }
            F[r] = f;
        }
#pragma unroll
        for (int col = 0; col < DD; ++col) {
            const float inv = 1.f / M[col][col];
#pragma unroll
            for (int r = col + 1; r < DD; ++r) {
                const float fac = M[r][col] * inv;
#pragma unroll
                for (int c = col + 1; c < DD; ++c) M[r][c] -= fac * M[col][c];
                F[r] -= fac * F[col];
            }
        }
#pragma unroll
        for (int r = DD - 1; r >= 0; --r) {
            float ssum = F[r];
#pragma unroll
            for (int c = r + 1; c < DD; ++c) ssum -= M[r][c] * a[c];
            a[r] = ssum / M[r][r];
        }
        float* op = out + (size_t)(s0 + s)*ZD;
#pragma unroll
        for (int c = 0; c < DD; ++c) { op[c] = v[c]; op[DD + c] = a[c]; }
    }
}

// ===========================================================================
// Fallback: round-9 monolith (verified; used only if ws_size is too small)
// ===========================================================================
__global__ void __launch_bounds__(512, 4)
lnn_main(const float* __restrict__ z,
         const float* __restrict__ W0, const float* __restrict__ b0,
         const float* __restrict__ b1, const float* __restrict__ b2,
         const float* __restrict__ W3,
         const _Float16* __restrict__ ws,
         float* __restrict__ out)
{
    __shared__ alignas(16) _Float16 Xt[64*XSTR + 24];
    __shared__ alignas(16) _Float16 Xb[64*XSTR + 24];
    __shared__ alignas(16) _Float16 Cf[5][8*CSTR];
    __shared__ alignas(16) _Float16 Xz[16*32];
    __shared__ alignas(16) _Float16 bsh[4*WSTR];
    __shared__ alignas(16) _Float16 w0t[NTAN*WSTR];
    __shared__ alignas(16) float gsh[8*16];
    __shared__ alignas(16) float Hr[64*16];

    const int tid  = threadIdx.x;
    const int wave = tid >> 6;
    const int lane = tid & 63;
    const int lm   = lane & 15;
    const int q    = lane >> 4;
    const int s0   = blockIdx.x * 8;

    const int mt0 = (wave < 5) ? wave*2 : (10 + (wave - 5));
    const int mtc = (wave < 5) ? 2 : 1;

    const half8* W1Tsw = (const half8*)(ws + OFF_W1T);
    const half8* W2Tsw = (const half8*)(ws + OFF_W2T);
    const half8* W1sw  = (const half8*)(ws + OFF_W1);
    const half8* W2sw  = (const half8*)(ws + OFF_W2);
    const half8* W0Tsw = (const half8*)(ws + OFF_W0T);
    const half8* W0sw  = (const half8*)(ws + OFF_W0);

    for (int idx = tid; idx < 16*32; idx += 512) {
        int s = idx >> 5, c = idx & 31;
        Xz[idx] = (s < 8 && c < ZD) ? (_Float16)z[(s0 + s)*ZD + c] : (_Float16)0.f;
    }
    if (tid < 24) {
        Xt[16*XSTR + tid] = (_Float16)0.f;
        Xb[16*XSTR + tid] = (_Float16)0.f;
        Xt[64*XSTR + tid] = (_Float16)0.f;
        Xb[64*XSTR + tid] = (_Float16)0.f;
    }
    for (int idx = tid; idx < 4*WSTR; idx += 512) {
        int l = idx / WSTR, u = idx % WSTR;
        float v = 0.f;
        if (u < HID) {
            if      (l == 0) v = b0[u];
            else if (l == 1) v = b1[u];
            else if (l == 2) v = b2[u];
            else             v = KSC * W3[u];
        }
        bsh[idx] = (_Float16)v;
    }
    for (int idx = tid; idx < NTAN*WSTR; idx += 512) {
        int t = idx / WSTR, u = idx % WSTR;
        w0t[idx] = (_Float16)((u < HID) ? SSC * W0[(DD + t)*HID + u] : 0.f);
    }
    __syncthreads();

    float4v acc1[2][1];

    {
        half8 xz = *(const half8*)(Xz + lm*32 + q*8);
#pragma unroll
        for (int m = 0; m < 2; ++m)
            if (m < mtc) {
                acc1[m][0] = (float4v){0.f,0.f,0.f,0.f};
                half8 a = W0Tsw[(mt0 + m)*64 + lane];
                acc1[m][0] = __builtin_amdgcn_mfma_f32_16x16x32_f16(a, xz, acc1[m][0], 0, 0, 0);
                const int ub = (mt0 + m)*16 + q*4;
                const bool padq = (mt0 + m == 12) && (q >= 2);
                half4v bb = *(const half4v*)(&bsh[0*WSTR + ub]);
                float h[4], p[4];
#pragma unroll
                for (int r = 0; r < 4; ++r) {
                    float av = acc1[m][0][r] + (float)bb[r];
                    sig_sp(av, h[r], p[r]);
                }
                if (!padq) *(half4v*)(&Xt[lm*XSTR + ub]) = pk4((float4v){h[0],h[1],h[2],h[3]});
                if (lm < 8) *(half4v*)(&Cf[0][lm*CSTR + ub]) = pk4((float4v){p[0],p[1],p[2],p[3]});
            }
    }
    __syncthreads();

    {
        if (mtc == 2) run_mv<1,2>(W1Tsw, Xt, mt0, lane, acc1);
        else          run_mv<1,1>(W1Tsw, Xt, mt0, lane, acc1);
#pragma unroll
        for (int m = 0; m < 2; ++m)
            if (m < mtc) {
                const int ub = (mt0 + m)*16 + q*4;
                const bool padq = (mt0 + m == 12) && (q >= 2);
                half4v bb = *(const half4v*)(&bsh[1*WSTR + ub]);
                float h[4], p[4];
#pragma unroll
                for (int r = 0; r < 4; ++r) {
                    float av = acc1[m][0][r] + (float)bb[r];
                    sig_sp(av, h[r], p[r]);
                }
                if (!padq) *(half4v*)(&Xb[lm*XSTR + ub]) = pk4((float4v){h[0],h[1],h[2],h[3]});
                if (lm < 8) *(half4v*)(&Cf[1][lm*CSTR + ub]) = pk4((float4v){p[0],p[1],p[2],p[3]});
            }
    }
    __syncthreads();

    {
        if (mtc == 2) run_mv<1,2>(W2Tsw, Xb, mt0, lane, acc1);
        else          run_mv<1,1>(W2Tsw, Xb, mt0, lane, acc1);
#pragma unroll
        for (int m = 0; m < 2; ++m)
            if (m < mtc) {
                const int ub = (mt0 + m)*16 + q*4;
                const bool padq = (mt0 + m == 12) && (q >= 2);
                half4v bb = *(const half4v*)(&bsh[2*WSTR + ub]);
                half4v w3 = *(const half4v*)(&bsh[3*WSTR + ub]);
                float d2[4], c2[4];
#pragma unroll
                for (int r = 0; r < 4; ++r) {
                    float av = acc1[m][0][r] + (float)bb[r];
                    float e = __expf(-fabsf(av));
                    float rr = 1.f / (1.f + e);
                    float sg = (av >= 0.f) ? rr : (1.f - rr);
                    float wk = (float)w3[r];
                    d2[r] = wk * sg;
                    c2[r] = wk * sg * (1.f - sg);
                }
                if (!padq) *(half4v*)(&Xt[lm*XSTR + ub]) = pk4((float4v){d2[0],d2[1],d2[2],d2[3]});
                if (lm < 8) *(half4v*)(&Cf[2][lm*CSTR + ub]) = pk4((float4v){c2[0],c2[1],c2[2],c2[3]});
            }
    }
    __syncthreads();

    {
        if (mtc == 2) run_mv<1,2>(W2sw, Xt, mt0, lane, acc1);
        else          run_mv<1,1>(W2sw, Xt, mt0, lane, acc1);
#pragma unroll
        for (int m = 0; m < 2; ++m)
            if (m < mtc) {
                const int ub = (mt0 + m)*16 + q*4;
                const bool padq = (mt0 + m == 12) && (q >= 2);
                half4v p1 = *(const half4v*)(&Cf[1][(lm & 7)*CSTR + ub]);
                half4v u1 = pk4(acc1[m][0]);
                half4v one = {(_Float16)1.f,(_Float16)1.f,(_Float16)1.f,(_Float16)1.f};
                if (!padq) *(half4v*)(&Xb[lm*XSTR + ub]) = u1 * p1;
                if (lm < 8) *(half4v*)(&Cf[3][lm*CSTR + ub]) = u1 * (one - p1);
            }
    }
    __syncthreads();

    {
        if (mtc == 2) run_mv<1,2>(W1sw, Xb, mt0, lane, acc1);
        else          run_mv<1,1>(W1sw, Xb, mt0, lane, acc1);
#pragma unroll
        for (int m = 0; m < 2; ++m)
            if (m < mtc) {
                const int ub = (mt0 + m)*16 + q*4;
                const bool padq = (mt0 + m == 12) && (q >= 2);
                half4v p0 = *(const half4v*)(&Cf[0][(lm & 7)*CSTR + ub]);
                half4v u0 = pk4(acc1[m][0]);
                half4v one = {(_Float16)1.f,(_Float16)1.f,(_Float16)1.f,(_Float16)1.f};
                half4v d0 = u0 * p0;
                if (!padq) *(half4v*)(&Xt[lm*XSTR + ub]) = d0;
                if (lm < 8) *(half4v*)(&Cf[4][lm*CSTR + ub]) = d0 * (one - p0);
            }
    }
    __syncthreads();

    if (wave == 0) {
        half8 aw[NKC];
#pragma unroll
        for (int kc = 0; kc < NKC; ++kc) aw[kc] = W0sw[kc*64 + lane];
        float4v gv = (float4v){0.f,0.f,0.f,0.f};
#pragma unroll
        for (int kc = 0; kc < NKC; ++kc) {
            half8 x = *(const half8*)(Xt + lm*XSTR + kc*32 + q*8);
            gv = __builtin_amdgcn_mfma_f32_16x16x32_f16(aw[kc], x, gv, 0, 0, 0);
        }
        if (lm < 8) {
            float4v go; go.x = gv.x*INV_K; go.y = gv.y*INV_K; go.z = gv.z*INV_K; go.w = gv.w*INV_K;
            *(float4v*)(&gsh[lm*16 + q*4]) = go;
        }
    } else {
        for (int idx = tid - 64; idx < 64*50; idx += 512 - 64) {
            int row = idx / 50, u = (idx % 50)*4;
            int s = row & 7, t = row >> 3;
            half4v p0 = *(const half4v*)(&Cf[0][s*CSTR + u]);
            half4v w0 = *(const half4v*)(&w0t[t*WSTR + u]);
            *(half4v*)(&Xb[row*XSTR + u]) = p0 * w0;
        }
    }
    __syncthreads();

    float4v acc4[2][NT4];
    half4v c3th1[2][NT4];

    {
        if (mtc == 2) run_mv<NT4,2>(W1Tsw, Xb, mt0, lane, acc4);
        else          run_mv<NT4,1>(W1Tsw, Xb, mt0, lane, acc4);
#pragma unroll
        for (int m = 0; m < 2; ++m)
            if (m < mtc) {
                const int ub = (mt0 + m)*16 + q*4;
                const bool padq = (mt0 + m == 12) && (q >= 2);
                half4v p1 = *(const half4v*)(&Cf[1][(lm & 7)*CSTR + ub]);
                half4v c3 = *(const half4v*)(&Cf[3][(lm & 7)*CSTR + ub]);
#pragma unroll
                for (int n = 0; n < NT4; ++n) {
                    half4v t = pk4(acc4[m][n]) * p1;
                    if (!padq) *(half4v*)(&Xt[(n*16 + lm)*XSTR + ub]) = t;
                    c3th1[m][n] = c3 * t;
                }
            }
    }
    __syncthreads();

    {
        if (mtc == 2) run_mv<NT4,2>(W2Tsw, Xt, mt0, lane, acc4);
        else          run_mv<NT4,1>(W2Tsw, Xt, mt0, lane, acc4);
#pragma unroll
        for (int m = 0; m < 2; ++m)
            if (m < mtc) {
                const int ub = (mt0 + m)*16 + q*4;
                const bool padq = (mt0 + m == 12) && (q >= 2);
                half4v c2 = *(const half4v*)(&Cf[2][(lm & 7)*CSTR + ub]);
#pragma unroll
                for (int n = 0; n < NT4; ++n)
                    if (!padq) *(half4v*)(&Xb[(n*16 + lm)*XSTR + ub]) = pk4(acc4[m][n]) * c2;
            }
    }
    __syncthreads();

    {
        if (mtc == 2) run_mv<NT4,2>(W2sw, Xb, mt0, lane, acc4);
        else          run_mv<NT4,1>(W2sw, Xb, mt0, lane, acc4);
#pragma unroll
        for (int m = 0; m < 2; ++m)
            if (m < mtc) {
                const int ub = (mt0 + m)*16 + q*4;
                const bool padq = (mt0 + m == 12) && (q >= 2);
                half4v p1 = *(const half4v*)(&Cf[1][(lm & 7)*CSTR + ub]);
#pragma unroll
                for (int n = 0; n < NT4; ++n)
                    if (!padq) *(half4v*)(&Xt[(n*16 + lm)*XSTR + ub]) = pk4(acc4[m][n]) * p1 + c3th1[m][n];
            }
    }
    __syncthreads();

    {
        if (mtc == 2) run_mv<NT4,2>(W1sw, Xt, mt0, lane, acc4);
        else          run_mv<NT4,1>(W1sw, Xt, mt0, lane, acc4);
#pragma unroll
        for (int m = 0; m < 2; ++m)
            if (m < mtc) {
                const int ub = (mt0 + m)*16 + q*4;
                const bool padq = (mt0 + m == 12) && (q >= 2);
                half4v p0 = *(const half4v*)(&Cf[0][(lm & 7)*CSTR + ub]);
                half4v c4 = *(const half4v*)(&Cf[4][(lm & 7)*CSTR + ub]);
#pragma unroll
                for (int n = 0; n < NT4; ++n) {
                    int t = n*2 + (lm >> 3);
                    half4v w0 = *(const half4v*)(&w0t[t*WSTR + ub]);
                    if (!padq) *(half4v*)(&Xb[(n*16 + lm)*XSTR + ub]) = pk4(acc4[m][n]) * p0 + c4 * w0;
                }
            }
    }
    __syncthreads();

    if (wave < 4) {
        half8 aw[NKC];
#pragma unroll
        for (int kc = 0; kc < NKC; ++kc) aw[kc] = W0sw[kc*64 + lane];
        float4v hacc = (float4v){0.f,0.f,0.f,0.f};
#pragma unroll
        for (int kc = 0; kc < NKC; ++kc) {
            half8 x = *(const half8*)(Xb + (wave*16 + lm)*XSTR + kc*32 + q*8);
            hacc = __builtin_amdgcn_mfma_f32_16x16x32_f16(aw[kc], x, hacc, 0, 0, 0);
        }
        int row = wave*16 + lm;
        float4v hv;
        hv.x = hacc.x*INV_KS; hv.y = hacc.y*INV_KS;
        hv.z = hacc.z*INV_KS; hv.w = hacc.w*INV_KS;
        *(float4v*)(&Hr[row*16 + q*4]) = hv;
    }
    __syncthreads();

    if (tid < 8) {
        const int s = tid;
        float M[DD][DD], F[DD], v[DD], a[DD];
#pragma unroll
        for (int c = 0; c < DD; ++c) v[c] = z[(s0 + s)*ZD + DD + c];
#pragma unroll
        for (int r = 0; r < DD; ++r) {
            float f = gsh[s*16 + r];
#pragma unroll
            for (int c = 0; c < DD; ++c) {
                M[r][c] = Hr[(r*8 + s)*16 + DD + c] + ((r == c) ? 2.f*EPSL : 0.f);
                f -= Hr[(r*8 + s)*16 + c] * v[c];
            }
            F[r] = f;
        }
#pragma unroll
        for (int col = 0; col < DD; ++col) {
            const float inv = 1.f / M[col][col];
#pragma unroll
            for (int r = col + 1; r < DD; ++r) {
                const float fac = M[r][col] * inv;
#pragma unroll
                for (int c = col + 1; c < DD; ++c) M[r][c] -= fac * M[col][c];
                F[r] -= fac * F[col];
            }
        }
#pragma unroll
        for (int r = DD - 1; r >= 0; --r) {
            float ssum = F[r];
#pragma unroll
            for (int c = r + 1; c < DD; ++c) ssum -= M[r][c] * a[c];
            a[r] = ssum / M[r][r];
        }
        float* op = out + (size_t)(s0 + s)*ZD;
#pragma unroll
        for (int c = 0; c < DD; ++c) { op[c] = v[c]; op[DD + c] = a[c]; }
    }
}

// ===========================================================================
extern "C" void kernel_launch(void* const* d_in, const int* in_sizes, int n_in,
                              void* d_out, int out_size, void* d_ws, size_t ws_size,
                              hipStream_t stream)
{
    const float* z  = (const float*)d_in[1];
    const float* W0 = (const float*)d_in[2];
    const float* b0 = (const float*)d_in[3];
    const float* W1 = (const float*)d_in[4];
    const float* b1 = (const float*)d_in[5];
    const float* W2 = (const float*)d_in[6];
    const float* b2 = (const float*)d_in[7];
    const float* W3 = (const float*)d_in[8];
    float* out = (float*)d_out;
    _Float16* ws = (_Float16*)d_ws;

    const int n = in_sizes[1] / (2*DD);

    prep<<<dim3((WS_HALFS + 255)/256), dim3(256), 0, stream>>>(W0, W1, W2, ws);

    const size_t w_bytes = (size_t)WS_HALFS * 2;
    const size_t g_bytes = (size_t)n * 16 * 4;
    const size_t cf_bytes = (size_t)5 * n * HID * 2;
    const size_t need = w_bytes + g_bytes + cf_bytes;

    if (ws_size >= need && (n % 16) == 0) {
        float* g = (float*)((char*)d_ws + w_bytes);
        _Float16* cf = (_Float16*)((char*)d_ws + w_bytes + g_bytes);
        lnn_fwd<<<dim3(n / 16), dim3(512), 0, stream>>>(z, b0, b1, b2, W3, ws, cf, g, n);
        lnn_tan<<<dim3(n / 8), dim3(512), 0, stream>>>(z, W0, ws, cf, g, out, n);
    } else {
        lnn_main<<<dim3(n / 8), dim3(512), 0, stream>>>(z, W0, b0, b1, b2, W3, ws, out);
    }
}